// Round 6
// baseline (849.007 us; speedup 1.0000x reference)
//
#include <hip/hip_runtime.h>

// SimpleRNN: B=16384, T=2048, I=1, H=20, O=1, fp32.
//
// Round-11. r10 post-mortem: quad-rcp was ~neutral => trans ops are ~4 cyc
// (quarter-rate), NOT ~20. Real cost model: 1 wave/SIMD issues a VALU inst
// only every ~5 cyc (per-wave cadence + dep latency); r8 showed 2 waves/SIMD
// reach ~2.4 cyc/inst effective. r9/r10 ran 1024 waves = 1/SIMD: ~40% of
// issue bandwidth unfillable.
// Changes vs r10:
//  (a) 8 batches/wave (cols 0-7 of the 16x16 MFMA; cols 8-15 duplicate) ->
//      2048 waves = 2 waves/SIMD. MFMA/batch doubles but MfmaUtil was 15%.
//  (b) rc-state folding (validated r6-r8): state r = rcp(exp2(z)+1);
//      W_hh pre-scaled by -2K, bias = K*(b_ih+b_hh+rowsum(W_hh)), W_ih by K
//      (K = 2*log2(e)); tanh's h = 1-2r reconstructed only in the epilogue.
//      Removes 8 in-loop fma; no in-loop masking (garbage hits zero A-slots).
//  (c) revert quad-rcp -> 8 direct v_rcp (shorter chain, fewer insts).
//
//   C = (-2K*W_hh) @ r^T via mfma_f32_16x16x32_bf16, layout as r9/r10
//   (verified): C col = lane&15 = batch, row = 4*(lane>>4)+reg == next B
//   fragment in-lane. K-slot map (A and B identical): j<4 -> c=4g+j,
//   j>=4 -> c=16+4g+(j-4), c>=20 zero-padded. Truncation split hi/lo,
//   3 MFMA terms per tile (hi*hi, lo*hi, hi*lo).
//
// Per wave-step: ~56 VALU + 6 MFMA for 8 batches; 2 waves/SIMD.

#define RNN_T 2048
#define RNN_H 20
#define RNN_B 16384
#define NT4   (RNN_T / 4)

typedef float f32x4  __attribute__((ext_vector_type(4)));
typedef short bf16x8 __attribute__((ext_vector_type(8)));
typedef int   i32x4  __attribute__((ext_vector_type(4)));

// D = [bf16(b) : bf16(a)] by truncation; a lands in the LOW short (even elem).
__device__ __forceinline__ int pk_trunc(float a, float b) {
    return __builtin_amdgcn_perm(__builtin_bit_cast(int, b),
                                 __builtin_bit_cast(int, a), 0x07060302);
}
__device__ __forceinline__ float trunc_bf(float a) {
    return __builtin_bit_cast(float,
                              (int)(__builtin_bit_cast(int, a) & 0xffff0000));
}

__attribute__((amdgpu_flat_work_group_size(256, 256), amdgpu_waves_per_eu(2)))
__global__ void rnn_fwd(const float* __restrict__ x,
                        const float* __restrict__ W_ih,
                        const float* __restrict__ W_hh,
                        const float* __restrict__ b_ih,
                        const float* __restrict__ b_hh,
                        const float* __restrict__ W_fc,
                        const float* __restrict__ b_fc,
                        float* __restrict__ out) {
    const int gid  = blockIdx.x * blockDim.x + threadIdx.x;
    const int lane = threadIdx.x & 63;
    const int wid  = gid >> 6;        // global wave index
    const int B0   = wid * 8;         // this wave's batch block (8 batches)
    const int col  = lane & 15;       // A-row m / B-col n; batch = B0+(col&7)
    const int g    = lane >> 4;       // k-block / C-row-block

    const float KS = 2.885390081777927f;  // 2*log2(e)
    const float WS = -2.0f * KS;          // W_hh scale

    // ---- Prologue: A fragments (W_hh * -2K, truncation split hi/lo) ----
    float w1[8], w2[8], l1[8], l2[8];
#pragma unroll
    for (int j = 0; j < 8; ++j) {
        const int c   = (j < 4) ? (4 * g + j) : (16 + 4 * g + (j - 4));
        const float m = (c < RNN_H) ? WS : 0.0f;
        const int cc  = (c < RNN_H) ? c : 0;
        w1[j] = m * W_hh[col * RNN_H + cc];                              // rows 0..15
        w2[j] = (col < 4) ? m * W_hh[(16 + col) * RNN_H + cc] : 0.0f;    // rows 16..19
        l1[j] = w1[j] - trunc_bf(w1[j]);
        l2[j] = w2[j] - trunc_bf(w2[j]);
    }
    i32x4 a1h, a1l, a2h, a2l;
    a1h.x = pk_trunc(w1[0], w1[1]); a1h.y = pk_trunc(w1[2], w1[3]);
    a1h.z = pk_trunc(w1[4], w1[5]); a1h.w = pk_trunc(w1[6], w1[7]);
    a1l.x = pk_trunc(l1[0], l1[1]); a1l.y = pk_trunc(l1[2], l1[3]);
    a1l.z = pk_trunc(l1[4], l1[5]); a1l.w = pk_trunc(l1[6], l1[7]);
    a2h.x = pk_trunc(w2[0], w2[1]); a2h.y = pk_trunc(w2[2], w2[3]);
    a2h.z = pk_trunc(w2[4], w2[5]); a2h.w = pk_trunc(w2[6], w2[7]);
    a2l.x = pk_trunc(l2[0], l2[1]); a2l.y = pk_trunc(l2[2], l2[3]);
    a2l.z = pk_trunc(l2[4], l2[5]); a2l.w = pk_trunc(l2[6], l2[7]);
    const bf16x8 A1h = __builtin_bit_cast(bf16x8, a1h);
    const bf16x8 A1l = __builtin_bit_cast(bf16x8, a1l);
    const bf16x8 A2h = __builtin_bit_cast(bf16x8, a2h);
    const bf16x8 A2l = __builtin_bit_cast(bf16x8, a2l);

    // C-init constants: z = K*(w_ih*x + b_ih + b_hh + rowsum(W_hh)) per row.
    f32x4 kwih1, kbias1, kwih2, kbias2;
#pragma unroll
    for (int reg = 0; reg < 4; ++reg) {
        const int r1 = 4 * g + reg;
        const int r2 = (16 + 4 * g + reg < RNN_H) ? (16 + 4 * g + reg) : (RNN_H - 1);
        float rs1 = 0.0f, rs2 = 0.0f;
#pragma unroll
        for (int c = 0; c < RNN_H; ++c) {
            rs1 += W_hh[r1 * RNN_H + c];
            rs2 += W_hh[r2 * RNN_H + c];
        }
        kwih1[reg]  = KS * W_ih[r1];
        kbias1[reg] = KS * (b_ih[r1] + b_hh[r1] + rs1);
        kwih2[reg]  = KS * W_ih[r2];
        kbias2[reg] = KS * (b_ih[r2] + b_hh[r2] + rs2);
    }

    // State r = rcp(exp2(z)+1); r = 0.5 <=> h = 0. 0.5 is bf16-exact -> lo=0.
    float r10 = 0.5f, r11 = 0.5f, r12 = 0.5f, r13 = 0.5f;
    float r20 = 0.5f, r21 = 0.5f, r22 = 0.5f, r23 = 0.5f;
    i32x4 bh0;
    bh0.x = pk_trunc(0.5f, 0.5f); bh0.y = bh0.x; bh0.z = bh0.x; bh0.w = bh0.x;
    bf16x8 Bh = __builtin_bit_cast(bf16x8, bh0);
    i32x4 zz; zz.x = 0; zz.y = 0; zz.z = 0; zz.w = 0;
    bf16x8 Bl = __builtin_bit_cast(bf16x8, zz);

    const float4* x4 = (const float4*)(x + (size_t)(B0 + (col & 7)) * RNN_T);

#define STEP(XS)                                                                 \
    do {                                                                         \
        f32x4 xx = {(XS), (XS), (XS), (XS)};                                     \
        f32x4 acc1 = __builtin_elementwise_fma(kwih1, xx, kbias1);               \
        f32x4 acc2 = __builtin_elementwise_fma(kwih2, xx, kbias2);               \
        acc1 = __builtin_amdgcn_mfma_f32_16x16x32_bf16(A1h, Bh, acc1, 0, 0, 0);  \
        acc2 = __builtin_amdgcn_mfma_f32_16x16x32_bf16(A2h, Bh, acc2, 0, 0, 0);  \
        acc1 = __builtin_amdgcn_mfma_f32_16x16x32_bf16(A1l, Bh, acc1, 0, 0, 0);  \
        acc2 = __builtin_amdgcn_mfma_f32_16x16x32_bf16(A2l, Bh, acc2, 0, 0, 0);  \
        acc1 = __builtin_amdgcn_mfma_f32_16x16x32_bf16(A1h, Bl, acc1, 0, 0, 0);  \
        acc2 = __builtin_amdgcn_mfma_f32_16x16x32_bf16(A2h, Bl, acc2, 0, 0, 0);  \
        r10 = __builtin_amdgcn_rcpf(__builtin_amdgcn_exp2f(acc1.x) + 1.0f);      \
        r11 = __builtin_amdgcn_rcpf(__builtin_amdgcn_exp2f(acc1.y) + 1.0f);      \
        r12 = __builtin_amdgcn_rcpf(__builtin_amdgcn_exp2f(acc1.z) + 1.0f);      \
        r13 = __builtin_amdgcn_rcpf(__builtin_amdgcn_exp2f(acc1.w) + 1.0f);      \
        r20 = __builtin_amdgcn_rcpf(__builtin_amdgcn_exp2f(acc2.x) + 1.0f);      \
        r21 = __builtin_amdgcn_rcpf(__builtin_amdgcn_exp2f(acc2.y) + 1.0f);      \
        r22 = __builtin_amdgcn_rcpf(__builtin_amdgcn_exp2f(acc2.z) + 1.0f);      \
        r23 = __builtin_amdgcn_rcpf(__builtin_amdgcn_exp2f(acc2.w) + 1.0f);      \
        {                                                                        \
            i32x4 bh, bl;                                                        \
            bh.x = pk_trunc(r10, r11);                                           \
            bh.y = pk_trunc(r12, r13);                                           \
            bh.z = pk_trunc(r20, r21);                                           \
            bh.w = pk_trunc(r22, r23);                                           \
            bl.x = pk_trunc(r10 - trunc_bf(r10), r11 - trunc_bf(r11));           \
            bl.y = pk_trunc(r12 - trunc_bf(r12), r13 - trunc_bf(r13));           \
            bl.z = pk_trunc(r20 - trunc_bf(r20), r21 - trunc_bf(r21));           \
            bl.w = pk_trunc(r22 - trunc_bf(r22), r23 - trunc_bf(r23));           \
            Bh = __builtin_bit_cast(bf16x8, bh);                                 \
            Bl = __builtin_bit_cast(bf16x8, bl);                                 \
        }                                                                        \
    } while (0)

    float4 xv = x4[0];
#pragma unroll 1
    for (int t4 = 0; t4 < NT4; ++t4) {
        const int tn = (t4 + 1 < NT4) ? (t4 + 1) : t4;
        const float4 xn = x4[tn];
        STEP(xv.x);
        STEP(xv.y);
        STEP(xv.z);
        STEP(xv.w);
        xv = xn;
    }
#undef STEP

    // Epilogue: h = 1-2r. Lane holds rows 4g..4g+3 (r1*) and, for g==0,
    // rows 16..19 (r2*); tile2 masked by mk2. Reduce g-groups: lanes
    // l, l^16, l^32, l^48 share col.
    const float mk2 = (g == 0) ? 1.0f : 0.0f;
    const float ms2 = -2.0f * mk2;
    float p = fmaf(-2.0f, r10, 1.0f) * W_fc[4 * g + 0];
    p = fmaf(fmaf(-2.0f, r11, 1.0f), W_fc[4 * g + 1], p);
    p = fmaf(fmaf(-2.0f, r12, 1.0f), W_fc[4 * g + 2], p);
    p = fmaf(fmaf(-2.0f, r13, 1.0f), W_fc[4 * g + 3], p);
    p = fmaf(fmaf(ms2, r20, mk2), W_fc[16], p);
    p = fmaf(fmaf(ms2, r21, mk2), W_fc[17], p);
    p = fmaf(fmaf(ms2, r22, mk2), W_fc[18], p);
    p = fmaf(fmaf(ms2, r23, mk2), W_fc[19], p);
    p += __shfl_xor(p, 16, 64);
    p += __shfl_xor(p, 32, 64);
    if (lane < 8) {
        const float z = p + b_fc[0];
        const float e = __builtin_amdgcn_exp2f(-1.4426950408889634f * z);
        out[B0 + lane] = __builtin_amdgcn_rcpf(1.0f + e);
    }
}

extern "C" void kernel_launch(void* const* d_in, const int* in_sizes, int n_in,
                              void* d_out, int out_size, void* d_ws, size_t ws_size,
                              hipStream_t stream) {
    const float* x    = (const float*)d_in[0];
    const float* W_ih = (const float*)d_in[1];
    const float* W_hh = (const float*)d_in[2];
    const float* b_ih = (const float*)d_in[3];
    const float* b_hh = (const float*)d_in[4];
    const float* W_fc = (const float*)d_in[5];
    const float* b_fc = (const float*)d_in[6];
    float* out = (float*)d_out;

    const int threads = (RNN_B / 8) * 64;  // 131072 = 2048 waves = 2/SIMD
    const int block   = 256;
    rnn_fwd<<<threads / block, block, 0, stream>>>(x, W_ih, W_hh, b_ih, b_hh,
                                                   W_fc, b_fc, out);
}

// Round 7
// 627.037 us; speedup vs baseline: 1.3540x; 1.3540x over previous
//
#include <hip/hip_runtime.h>

// SimpleRNN: B=16384, T=2048, I=1, H=20, O=1, fp32.
//
// Round-12. Unified cost model from r8/r10/r11 (recomputed): ~5-6 busy-cyc
// per SOURCE instruction in every config -- occupancy (r11), in-thread ILP
// (r7), trans-batching (r10) all failed to move it. Only inst-count
// reduction wins (r9). r11's regression = per-batch insts rose (act/pack
// scales with C-regs, not batches) when batches/wave halved.
// => r12 = r10's 16-batch/wave structure (1024 waves) + r11's two validated
// per-inst cuts, WITHOUT the occupancy change:
//  (a) rc-state folding: state r = rcp(exp2(z)+1); W_hh pre-scaled by -2K,
//      bias = K*(b_ih+b_hh+rowsum(W_hh)), W_ih by K (K = 2*log2(e)).
//      Kills the 8 in-loop h=1-2r fmas + all in-loop masking (tile2 garbage
//      feeds zero-padded A-columns; validated r11).
//  (b) direct 8x v_rcp (quad-trick reverted: trans are cheap, r10).
// Per wave-step: ~56 src VALU + 6 MFMA for 16 batches (3.5 insts/batch vs
// r10 4.75 / r11 7.0).
//
//   C = (-2K*W_hh) @ r^T via mfma_f32_16x16x32_bf16 (layout verified r9):
//   C col = lane&15 = batch, row = 4*(lane>>4)+reg == next B fragment
//   in-lane. K-slot map (A,B identical): j<4 -> c=4g+j, j>=4 -> 16+4g+(j-4),
//   c>=20 zero-padded. Truncation split hi/lo; 3 terms per tile
//   (AhiBh, AloBh, AhiBl). No DPP/LDS/cross-lane in the loop.
//
// 16 batches/wave -> 65536 threads = 1024 waves = 1 wave/SIMD, full chip.

#define RNN_T 2048
#define RNN_H 20
#define RNN_B 16384
#define NT4   (RNN_T / 4)

typedef float f32x4  __attribute__((ext_vector_type(4)));
typedef short bf16x8 __attribute__((ext_vector_type(8)));
typedef int   i32x4  __attribute__((ext_vector_type(4)));

// D = [bf16(b) : bf16(a)] by truncation; a lands in the LOW short (even elem).
__device__ __forceinline__ int pk_trunc(float a, float b) {
    return __builtin_amdgcn_perm(__builtin_bit_cast(int, b),
                                 __builtin_bit_cast(int, a), 0x07060302);
}
__device__ __forceinline__ float trunc_bf(float a) {
    return __builtin_bit_cast(float,
                              (int)(__builtin_bit_cast(int, a) & 0xffff0000));
}

__attribute__((amdgpu_flat_work_group_size(256, 256)))
__global__ void rnn_fwd(const float* __restrict__ x,
                        const float* __restrict__ W_ih,
                        const float* __restrict__ W_hh,
                        const float* __restrict__ b_ih,
                        const float* __restrict__ b_hh,
                        const float* __restrict__ W_fc,
                        const float* __restrict__ b_fc,
                        float* __restrict__ out) {
    const int gid  = blockIdx.x * blockDim.x + threadIdx.x;
    const int lane = threadIdx.x & 63;
    const int wid  = gid >> 6;        // global wave index
    const int B0   = wid * 16;        // this wave's batch block
    const int col  = lane & 15;       // batch slot / A-row m / B-col n
    const int g    = lane >> 4;       // k-block / C-row-block

    const float KS = 2.885390081777927f;  // 2*log2(e)
    const float WS = -2.0f * KS;          // W_hh scale

    // ---- Prologue: A fragments (W_hh * -2K, truncation split hi/lo) ----
    float w1[8], w2[8], l1[8], l2[8];
#pragma unroll
    for (int j = 0; j < 8; ++j) {
        const int c   = (j < 4) ? (4 * g + j) : (16 + 4 * g + (j - 4));
        const float m = (c < RNN_H) ? WS : 0.0f;
        const int cc  = (c < RNN_H) ? c : 0;
        w1[j] = m * W_hh[col * RNN_H + cc];                              // rows 0..15
        w2[j] = (col < 4) ? m * W_hh[(16 + col) * RNN_H + cc] : 0.0f;    // rows 16..19
        l1[j] = w1[j] - trunc_bf(w1[j]);
        l2[j] = w2[j] - trunc_bf(w2[j]);
    }
    i32x4 a1h, a1l, a2h, a2l;
    a1h.x = pk_trunc(w1[0], w1[1]); a1h.y = pk_trunc(w1[2], w1[3]);
    a1h.z = pk_trunc(w1[4], w1[5]); a1h.w = pk_trunc(w1[6], w1[7]);
    a1l.x = pk_trunc(l1[0], l1[1]); a1l.y = pk_trunc(l1[2], l1[3]);
    a1l.z = pk_trunc(l1[4], l1[5]); a1l.w = pk_trunc(l1[6], l1[7]);
    a2h.x = pk_trunc(w2[0], w2[1]); a2h.y = pk_trunc(w2[2], w2[3]);
    a2h.z = pk_trunc(w2[4], w2[5]); a2h.w = pk_trunc(w2[6], w2[7]);
    a2l.x = pk_trunc(l2[0], l2[1]); a2l.y = pk_trunc(l2[2], l2[3]);
    a2l.z = pk_trunc(l2[4], l2[5]); a2l.w = pk_trunc(l2[6], l2[7]);
    const bf16x8 A1h = __builtin_bit_cast(bf16x8, a1h);
    const bf16x8 A1l = __builtin_bit_cast(bf16x8, a1l);
    const bf16x8 A2h = __builtin_bit_cast(bf16x8, a2h);
    const bf16x8 A2l = __builtin_bit_cast(bf16x8, a2l);

    // C-init constants: z = K*(w_ih*x + b_ih + b_hh + rowsum(W_hh)) per row.
    f32x4 kwih1, kbias1, kwih2, kbias2;
#pragma unroll
    for (int reg = 0; reg < 4; ++reg) {
        const int r1 = 4 * g + reg;
        const int r2 = (16 + 4 * g + reg < RNN_H) ? (16 + 4 * g + reg) : (RNN_H - 1);
        float rs1 = 0.0f, rs2 = 0.0f;
#pragma unroll
        for (int c = 0; c < RNN_H; ++c) {
            rs1 += W_hh[r1 * RNN_H + c];
            rs2 += W_hh[r2 * RNN_H + c];
        }
        kwih1[reg]  = KS * W_ih[r1];
        kbias1[reg] = KS * (b_ih[r1] + b_hh[r1] + rs1);
        kwih2[reg]  = KS * W_ih[r2];
        kbias2[reg] = KS * (b_ih[r2] + b_hh[r2] + rs2);
    }

    // State r = rcp(exp2(z)+1); r = 0.5 <=> h = 0. 0.5 is bf16-exact -> lo=0.
    float r10 = 0.5f, r11 = 0.5f, r12 = 0.5f, r13 = 0.5f;
    float r20 = 0.5f, r21 = 0.5f, r22 = 0.5f, r23 = 0.5f;
    i32x4 bh0;
    bh0.x = pk_trunc(0.5f, 0.5f); bh0.y = bh0.x; bh0.z = bh0.x; bh0.w = bh0.x;
    bf16x8 Bh = __builtin_bit_cast(bf16x8, bh0);
    i32x4 zz; zz.x = 0; zz.y = 0; zz.z = 0; zz.w = 0;
    bf16x8 Bl = __builtin_bit_cast(bf16x8, zz);

    const float4* x4 = (const float4*)(x + (size_t)(B0 + col) * RNN_T);

#define STEP(XS)                                                                 \
    do {                                                                         \
        f32x4 xx = {(XS), (XS), (XS), (XS)};                                     \
        f32x4 acc1 = __builtin_elementwise_fma(kwih1, xx, kbias1);               \
        f32x4 acc2 = __builtin_elementwise_fma(kwih2, xx, kbias2);               \
        acc1 = __builtin_amdgcn_mfma_f32_16x16x32_bf16(A1h, Bh, acc1, 0, 0, 0);  \
        acc2 = __builtin_amdgcn_mfma_f32_16x16x32_bf16(A2h, Bh, acc2, 0, 0, 0);  \
        acc1 = __builtin_amdgcn_mfma_f32_16x16x32_bf16(A1l, Bh, acc1, 0, 0, 0);  \
        acc2 = __builtin_amdgcn_mfma_f32_16x16x32_bf16(A2l, Bh, acc2, 0, 0, 0);  \
        acc1 = __builtin_amdgcn_mfma_f32_16x16x32_bf16(A1h, Bl, acc1, 0, 0, 0);  \
        acc2 = __builtin_amdgcn_mfma_f32_16x16x32_bf16(A2h, Bl, acc2, 0, 0, 0);  \
        r10 = __builtin_amdgcn_rcpf(__builtin_amdgcn_exp2f(acc1.x) + 1.0f);      \
        r11 = __builtin_amdgcn_rcpf(__builtin_amdgcn_exp2f(acc1.y) + 1.0f);      \
        r12 = __builtin_amdgcn_rcpf(__builtin_amdgcn_exp2f(acc1.z) + 1.0f);      \
        r13 = __builtin_amdgcn_rcpf(__builtin_amdgcn_exp2f(acc1.w) + 1.0f);      \
        r20 = __builtin_amdgcn_rcpf(__builtin_amdgcn_exp2f(acc2.x) + 1.0f);      \
        r21 = __builtin_amdgcn_rcpf(__builtin_amdgcn_exp2f(acc2.y) + 1.0f);      \
        r22 = __builtin_amdgcn_rcpf(__builtin_amdgcn_exp2f(acc2.z) + 1.0f);      \
        r23 = __builtin_amdgcn_rcpf(__builtin_amdgcn_exp2f(acc2.w) + 1.0f);      \
        {                                                                        \
            i32x4 bh, bl;                                                        \
            bh.x = pk_trunc(r10, r11);                                           \
            bh.y = pk_trunc(r12, r13);                                           \
            bh.z = pk_trunc(r20, r21);                                           \
            bh.w = pk_trunc(r22, r23);                                           \
            bl.x = pk_trunc(r10 - trunc_bf(r10), r11 - trunc_bf(r11));           \
            bl.y = pk_trunc(r12 - trunc_bf(r12), r13 - trunc_bf(r13));           \
            bl.z = pk_trunc(r20 - trunc_bf(r20), r21 - trunc_bf(r21));           \
            bl.w = pk_trunc(r22 - trunc_bf(r22), r23 - trunc_bf(r23));           \
            Bh = __builtin_bit_cast(bf16x8, bh);                                 \
            Bl = __builtin_bit_cast(bf16x8, bl);                                 \
        }                                                                        \
    } while (0)

    float4 xv = x4[0];
#pragma unroll 1
    for (int t4 = 0; t4 < NT4; ++t4) {
        const int tn = (t4 + 1 < NT4) ? (t4 + 1) : t4;
        const float4 xn = x4[tn];
        STEP(xv.x);
        STEP(xv.y);
        STEP(xv.z);
        STEP(xv.w);
        xv = xn;
    }
#undef STEP

    // Epilogue: h = 1-2r. Lane holds rows 4g..4g+3 (r1*) and, for g==0,
    // rows 16..19 (r2*); tile2 masked here (not in-loop). Reduce g-groups:
    // lanes l, l^16, l^32, l^48 share col.
    const float mk2 = (g == 0) ? 1.0f : 0.0f;
    const float ms2 = -2.0f * mk2;
    float p = fmaf(-2.0f, r10, 1.0f) * W_fc[4 * g + 0];
    p = fmaf(fmaf(-2.0f, r11, 1.0f), W_fc[4 * g + 1], p);
    p = fmaf(fmaf(-2.0f, r12, 1.0f), W_fc[4 * g + 2], p);
    p = fmaf(fmaf(-2.0f, r13, 1.0f), W_fc[4 * g + 3], p);
    p = fmaf(fmaf(ms2, r20, mk2), W_fc[16], p);
    p = fmaf(fmaf(ms2, r21, mk2), W_fc[17], p);
    p = fmaf(fmaf(ms2, r22, mk2), W_fc[18], p);
    p = fmaf(fmaf(ms2, r23, mk2), W_fc[19], p);
    p += __shfl_xor(p, 16, 64);
    p += __shfl_xor(p, 32, 64);
    if (lane < 16) {
        const float z = p + b_fc[0];
        const float e = __builtin_amdgcn_exp2f(-1.4426950408889634f * z);
        out[B0 + lane] = __builtin_amdgcn_rcpf(1.0f + e);
    }
}

extern "C" void kernel_launch(void* const* d_in, const int* in_sizes, int n_in,
                              void* d_out, int out_size, void* d_ws, size_t ws_size,
                              hipStream_t stream) {
    const float* x    = (const float*)d_in[0];
    const float* W_ih = (const float*)d_in[1];
    const float* W_hh = (const float*)d_in[2];
    const float* b_ih = (const float*)d_in[3];
    const float* b_hh = (const float*)d_in[4];
    const float* W_fc = (const float*)d_in[5];
    const float* b_fc = (const float*)d_in[6];
    float* out = (float*)d_out;

    const int threads = (RNN_B / 16) * 64;  // 65536 = 1024 waves = 1/SIMD
    const int block   = 256;
    rnn_fwd<<<threads / block, block, 0, stream>>>(x, W_ih, W_hh, b_ih, b_hh,
                                                   W_fc, b_fc, out);
}

// Round 10
// 600.328 us; speedup vs baseline: 1.4142x; 1.0445x over previous
//
#include <hip/hip_runtime.h>

// SimpleRNN: B=16384, T=2048, I=1, H=20, O=1, fp32.
//
// Round-14. r13 FAILED numerically (absmax 0.113): bf16-only state is a
// 2^-10 ABSOLUTE error on r (r~0.5) -> 2^-9 absolute on h even near h=0,
// random-walking over 2048 steps. State hi/lo split is mandatory.
// => revert to r12 numerics BIT-IDENTICAL (known pass, 518 us counter),
// with one zero-risk pack cut:
//   lo-computation reuses the packed bh words: hi(r_even) = bh<<16,
//   hi(r_odd) = bh & 0xffff0000 (bit-identical to trunc_bf), and the
//   subtractions are formed as v2f pairs so the compiler can emit
//   v_pk_add_f32 (8 v_sub -> 4 pk). Pack 24 -> ~20 insts; step 64 -> ~60.
//
//   C = (-2K*W_hh) @ r^T via mfma_f32_16x16x32_bf16 (layout verified r9):
//   C col = lane&15 = batch, row = 4*(lane>>4)+reg == next B fragment
//   in-lane. K-slot map (A,B identical): j<4 -> c=4g+j, j>=4 -> 16+4g+(j-4),
//   c>=20 zero-padded. rc-state folding: state r = rcp(exp2(z)+1); W_hh
//   pre-scaled by -2K, bias = K*(b_ih+b_hh+rowsum(W_hh)), W_ih by K
//   (K = 2*log2(e)); h = 1-2r only in epilogue. Truncation split hi/lo on
//   BOTH weights and state; 3 MFMA terms per tile (AhBh, AlBh, AhBl).
//
// 16 batches/wave -> 65536 threads = 1024 waves = 1 wave/SIMD, full chip.

#define RNN_T 2048
#define RNN_H 20
#define RNN_B 16384
#define NT4   (RNN_T / 4)

typedef float f32x4  __attribute__((ext_vector_type(4)));
typedef float v2f    __attribute__((ext_vector_type(2)));
typedef short bf16x8 __attribute__((ext_vector_type(8)));
typedef int   i32x4  __attribute__((ext_vector_type(4)));

// D = [bf16(b) : bf16(a)] by truncation; a lands in the LOW short (even elem).
__device__ __forceinline__ int pk_trunc(float a, float b) {
    return __builtin_amdgcn_perm(__builtin_bit_cast(int, b),
                                 __builtin_bit_cast(int, a), 0x07060302);
}
__device__ __forceinline__ float trunc_bf(float a) {
    return __builtin_bit_cast(float,
                              (int)(__builtin_bit_cast(int, a) & 0xffff0000));
}
// Recover the two truncated f32 values from a packed [bf16:bf16] word.
// Bit-identical to trunc_bf of the original inputs.
__device__ __forceinline__ float lo16f(int w) {
    return __builtin_bit_cast(float, (int)(w << 16));
}
__device__ __forceinline__ float hi16f(int w) {
    return __builtin_bit_cast(float, (int)(w & (int)0xffff0000u));
}

__attribute__((amdgpu_flat_work_group_size(256, 256)))
__global__ void rnn_fwd(const float* __restrict__ x,
                        const float* __restrict__ W_ih,
                        const float* __restrict__ W_hh,
                        const float* __restrict__ b_ih,
                        const float* __restrict__ b_hh,
                        const float* __restrict__ W_fc,
                        const float* __restrict__ b_fc,
                        float* __restrict__ out) {
    const int gid  = blockIdx.x * blockDim.x + threadIdx.x;
    const int lane = threadIdx.x & 63;
    const int wid  = gid >> 6;        // global wave index
    const int B0   = wid * 16;        // this wave's batch block
    const int col  = lane & 15;       // batch slot / A-row m / B-col n
    const int g    = lane >> 4;       // k-block / C-row-block

    const float KS = 2.885390081777927f;  // 2*log2(e)
    const float WS = -2.0f * KS;          // W_hh scale

    // ---- Prologue: A fragments (W_hh * -2K, truncation split hi/lo) ----
    float w1[8], w2[8], l1[8], l2[8];
#pragma unroll
    for (int j = 0; j < 8; ++j) {
        const int c   = (j < 4) ? (4 * g + j) : (16 + 4 * g + (j - 4));
        const float m = (c < RNN_H) ? WS : 0.0f;
        const int cc  = (c < RNN_H) ? c : 0;
        w1[j] = m * W_hh[col * RNN_H + cc];                              // rows 0..15
        w2[j] = (col < 4) ? m * W_hh[(16 + col) * RNN_H + cc] : 0.0f;    // rows 16..19
        l1[j] = w1[j] - trunc_bf(w1[j]);
        l2[j] = w2[j] - trunc_bf(w2[j]);
    }
    i32x4 a1h, a1l, a2h, a2l;
    a1h.x = pk_trunc(w1[0], w1[1]); a1h.y = pk_trunc(w1[2], w1[3]);
    a1h.z = pk_trunc(w1[4], w1[5]); a1h.w = pk_trunc(w1[6], w1[7]);
    a1l.x = pk_trunc(l1[0], l1[1]); a1l.y = pk_trunc(l1[2], l1[3]);
    a1l.z = pk_trunc(l1[4], l1[5]); a1l.w = pk_trunc(l1[6], l1[7]);
    a2h.x = pk_trunc(w2[0], w2[1]); a2h.y = pk_trunc(w2[2], w2[3]);
    a2h.z = pk_trunc(w2[4], w2[5]); a2h.w = pk_trunc(w2[6], w2[7]);
    a2l.x = pk_trunc(l2[0], l2[1]); a2l.y = pk_trunc(l2[2], l2[3]);
    a2l.z = pk_trunc(l2[4], l2[5]); a2l.w = pk_trunc(l2[6], l2[7]);
    const bf16x8 A1h = __builtin_bit_cast(bf16x8, a1h);
    const bf16x8 A1l = __builtin_bit_cast(bf16x8, a1l);
    const bf16x8 A2h = __builtin_bit_cast(bf16x8, a2h);
    const bf16x8 A2l = __builtin_bit_cast(bf16x8, a2l);

    // C-init constants: z = K*(w_ih*x + b_ih + b_hh + rowsum(W_hh)) per row.
    f32x4 kwih1, kbias1, kwih2, kbias2;
#pragma unroll
    for (int reg = 0; reg < 4; ++reg) {
        const int r1 = 4 * g + reg;
        const int r2 = (16 + 4 * g + reg < RNN_H) ? (16 + 4 * g + reg) : (RNN_H - 1);
        float rs1 = 0.0f, rs2 = 0.0f;
#pragma unroll
        for (int c = 0; c < RNN_H; ++c) {
            rs1 += W_hh[r1 * RNN_H + c];
            rs2 += W_hh[r2 * RNN_H + c];
        }
        kwih1[reg]  = KS * W_ih[r1];
        kbias1[reg] = KS * (b_ih[r1] + b_hh[r1] + rs1);
        kwih2[reg]  = KS * W_ih[r2];
        kbias2[reg] = KS * (b_ih[r2] + b_hh[r2] + rs2);
    }

    // State r = rcp(exp2(z)+1); r = 0.5 <=> h = 0. 0.5 is bf16-exact -> lo=0.
    float r10 = 0.5f, r11 = 0.5f, r12 = 0.5f, r13 = 0.5f;
    float r20 = 0.5f, r21 = 0.5f, r22 = 0.5f, r23 = 0.5f;
    i32x4 bh0;
    bh0.x = pk_trunc(0.5f, 0.5f); bh0.y = bh0.x; bh0.z = bh0.x; bh0.w = bh0.x;
    bf16x8 Bh = __builtin_bit_cast(bf16x8, bh0);
    i32x4 zz; zz.x = 0; zz.y = 0; zz.z = 0; zz.w = 0;
    bf16x8 Bl = __builtin_bit_cast(bf16x8, zz);

    const float4* x4 = (const float4*)(x + (size_t)(B0 + col) * RNN_T);

#define STEP(XS)                                                                 \
    do {                                                                         \
        f32x4 xx = {(XS), (XS), (XS), (XS)};                                     \
        f32x4 acc1 = __builtin_elementwise_fma(kwih1, xx, kbias1);               \
        f32x4 acc2 = __builtin_elementwise_fma(kwih2, xx, kbias2);               \
        acc1 = __builtin_amdgcn_mfma_f32_16x16x32_bf16(A1h, Bh, acc1, 0, 0, 0);  \
        acc2 = __builtin_amdgcn_mfma_f32_16x16x32_bf16(A2h, Bh, acc2, 0, 0, 0);  \
        acc1 = __builtin_amdgcn_mfma_f32_16x16x32_bf16(A1l, Bh, acc1, 0, 0, 0);  \
        acc2 = __builtin_amdgcn_mfma_f32_16x16x32_bf16(A2l, Bh, acc2, 0, 0, 0);  \
        acc1 = __builtin_amdgcn_mfma_f32_16x16x32_bf16(A1h, Bl, acc1, 0, 0, 0);  \
        acc2 = __builtin_amdgcn_mfma_f32_16x16x32_bf16(A2h, Bl, acc2, 0, 0, 0);  \
        r10 = __builtin_amdgcn_rcpf(__builtin_amdgcn_exp2f(acc1.x) + 1.0f);      \
        r11 = __builtin_amdgcn_rcpf(__builtin_amdgcn_exp2f(acc1.y) + 1.0f);      \
        r12 = __builtin_amdgcn_rcpf(__builtin_amdgcn_exp2f(acc1.z) + 1.0f);      \
        r13 = __builtin_amdgcn_rcpf(__builtin_amdgcn_exp2f(acc1.w) + 1.0f);      \
        r20 = __builtin_amdgcn_rcpf(__builtin_amdgcn_exp2f(acc2.x) + 1.0f);      \
        r21 = __builtin_amdgcn_rcpf(__builtin_amdgcn_exp2f(acc2.y) + 1.0f);      \
        r22 = __builtin_amdgcn_rcpf(__builtin_amdgcn_exp2f(acc2.z) + 1.0f);      \
        r23 = __builtin_amdgcn_rcpf(__builtin_amdgcn_exp2f(acc2.w) + 1.0f);      \
        {                                                                        \
            i32x4 bh, bl;                                                        \
            bh.x = pk_trunc(r10, r11);                                           \
            bh.y = pk_trunc(r12, r13);                                           \
            bh.z = pk_trunc(r20, r21);                                           \
            bh.w = pk_trunc(r22, r23);                                           \
            /* lo pairs: recover hi from packed words (bit-identical to     */   \
            /* trunc_bf) and subtract as v2f so pk_add can fuse.            */   \
            v2f p0 = {r10, r11}, p1 = {r12, r13};                                \
            v2f p2 = {r20, r21}, p3 = {r22, r23};                               \
            v2f h0 = {lo16f(bh.x), hi16f(bh.x)};                                 \
            v2f h1 = {lo16f(bh.y), hi16f(bh.y)};                                 \
            v2f h2 = {lo16f(bh.z), hi16f(bh.z)};                                 \
            v2f h3 = {lo16f(bh.w), hi16f(bh.w)};                                 \
            v2f q0 = p0 - h0, q1 = p1 - h1, q2 = p2 - h2, q3 = p3 - h3;          \
            bl.x = pk_trunc(q0.x, q0.y);                                         \
            bl.y = pk_trunc(q1.x, q1.y);                                         \
            bl.z = pk_trunc(q2.x, q2.y);                                         \
            bl.w = pk_trunc(q3.x, q3.y);                                         \
            Bh = __builtin_bit_cast(bf16x8, bh);                                 \
            Bl = __builtin_bit_cast(bf16x8, bl);                                 \
        }                                                                        \
    } while (0)

    float4 xv = x4[0];
#pragma unroll 1
    for (int t4 = 0; t4 < NT4; ++t4) {
        const int tn = (t4 + 1 < NT4) ? (t4 + 1) : t4;
        const float4 xn = x4[tn];
        STEP(xv.x);
        STEP(xv.y);
        STEP(xv.z);
        STEP(xv.w);
        xv = xn;
    }
#undef STEP

    // Epilogue: h = 1-2r. Lane holds rows 4g..4g+3 (r1*) and, for g==0,
    // rows 16..19 (r2*); tile2 masked here (not in-loop). Reduce g-groups:
    // lanes l, l^16, l^32, l^48 share col.
    const float mk2 = (g == 0) ? 1.0f : 0.0f;
    const float ms2 = -2.0f * mk2;
    float p = fmaf(-2.0f, r10, 1.0f) * W_fc[4 * g + 0];
    p = fmaf(fmaf(-2.0f, r11, 1.0f), W_fc[4 * g + 1], p);
    p = fmaf(fmaf(-2.0f, r12, 1.0f), W_fc[4 * g + 2], p);
    p = fmaf(fmaf(-2.0f, r13, 1.0f), W_fc[4 * g + 3], p);
    p = fmaf(fmaf(ms2, r20, mk2), W_fc[16], p);
    p = fmaf(fmaf(ms2, r21, mk2), W_fc[17], p);
    p = fmaf(fmaf(ms2, r22, mk2), W_fc[18], p);
    p = fmaf(fmaf(ms2, r23, mk2), W_fc[19], p);
    p += __shfl_xor(p, 16, 64);
    p += __shfl_xor(p, 32, 64);
    if (lane < 16) {
        const float z = p + b_fc[0];
        const float e = __builtin_amdgcn_exp2f(-1.4426950408889634f * z);
        out[B0 + lane] = __builtin_amdgcn_rcpf(1.0f + e);
    }
}

extern "C" void kernel_launch(void* const* d_in, const int* in_sizes, int n_in,
                              void* d_out, int out_size, void* d_ws, size_t ws_size,
                              hipStream_t stream) {
    const float* x    = (const float*)d_in[0];
    const float* W_ih = (const float*)d_in[1];
    const float* W_hh = (const float*)d_in[2];
    const float* b_ih = (const float*)d_in[3];
    const float* b_hh = (const float*)d_in[4];
    const float* W_fc = (const float*)d_in[5];
    const float* b_fc = (const float*)d_in[6];
    float* out = (float*)d_out;

    const int threads = (RNN_B / 16) * 64;  // 65536 = 1024 waves = 1/SIMD
    const int block   = 256;
    rnn_fwd<<<threads / block, block, 0, stream>>>(x, W_ih, W_hh, b_ih, b_hh,
                                                   W_fc, b_fc, out);
}